// Round 10
// baseline (176.177 us; speedup 1.0000x reference)
//
#include <hip/hip_runtime.h>

typedef float    f32x4 __attribute__((ext_vector_type(4)));
typedef __bf16   bf16x8 __attribute__((ext_vector_type(8)));
typedef _Float16 f16x4 __attribute__((ext_vector_type(4)));

typedef __attribute__((address_space(1))) const void gas_void;
typedef __attribute__((address_space(3))) void las_void;

static __device__ __forceinline__ unsigned short f2bf(float f) {
  union { float f; unsigned int u; } a; a.f = f;
  unsigned int r = (a.u + 0x7FFFu + ((a.u >> 16) & 1u)) >> 16;
  return (unsigned short)r;
}

// 1/sqrt(17) * log2(e): folded into Wq and posW_q so softmax uses exp2 directly
#define QSCALE_L2E 0.34992146f

// Weights -> bf16 MFMA fragments (A-frag for swapped Q/K proj, B-frag for
// normal V proj; identical lane mapping).
// wf[((w*32 + n*4 + kk)*512) + p*8 + i] = W_w[kk*32+(p>>4)*8+i][n*16+(p&15)]
__global__ void prep_weights(const float* __restrict__ Wq, const float* __restrict__ Wk,
                             const float* __restrict__ Wv, unsigned short* __restrict__ wf) {
  int idx = blockIdx.x * 256 + threadIdx.x;
  if (idx >= 3 * 8 * 4 * 64 * 8) return;
  int i  = idx & 7;
  int p  = (idx >> 3) & 63;
  int kk = (idx >> 9) & 3;
  int n  = (idx >> 11) & 7;
  int w  = idx >> 14;
  const float* W = (w == 0) ? Wq : ((w == 1) ? Wk : Wv);
  float val = W[(kk * 32 + (p >> 4) * 8 + i) * 128 + n * 16 + (p & 15)];
  if (w == 0) val *= QSCALE_L2E;
  wf[idx] = f2bf(val);
}

// posW[w][t][d] accumulator-init fragments, per lane:
//  w<2 (swapped):  acc[r] = posW[t=l&15][d=h*16+(l>>4)*4+r]
//  w==2 (normal):  acc[r] = posW[t=(l>>4)*4+r][d=h*16+(l&15)]
__global__ void prep_posw(const float* __restrict__ pos, const float* __restrict__ Wq,
                          const float* __restrict__ Wk, const float* __restrict__ Wv,
                          float* __restrict__ pw) {
  int idx = blockIdx.x * 256 + threadIdx.x;
  if (idx >= 3 * 8 * 64 * 4) return;
  int r = idx & 3;
  int l = (idx >> 2) & 63;
  int h = (idx >> 8) & 7;
  int w = idx >> 11;
  const float* W = (w == 0) ? Wq : ((w == 1) ? Wk : Wv);
  int t, d;
  if (w < 2) { t = l & 15;            d = h * 16 + (l >> 4) * 4 + r; }
  else       { t = (l >> 4) * 4 + r;  d = h * 16 + (l & 15); }
  float s = 0.f;
  for (int k = 0; k < 128; ++k) s += pos[t * 128 + k] * W[k * 128 + d];
  if (w == 0) s *= QSCALE_L2E;
  pw[idx] = s;
}

// R9 structure (173 µs) at 2x wave concurrency: 8 waves/block, 1 head/wave,
// same 4-batch double-buffered DMA window. 2 blocks/CU -> 16 waves/CU
// (4/SIMD). Wave w DMAs chunks (w&1)*4..+3 of batch w>>1, computes head w for
// all 4 batches, stores pass-through cols w*16..+15.
__global__ void __launch_bounds__(512, 4)
attn_main(const float* __restrict__ xin, const float* __restrict__ pos,
          const unsigned short* __restrict__ wfrag, const float* __restrict__ pw,
          float* __restrict__ out, int B) {
  // [buf][batch g][chunk c=0..7][lane]: chunk c=(kk<<1)|half holds
  // x[l&15][kk*32 + (l>>4)*8 + half*4 .. +3]
  __shared__ __align__(16) float lx[2][4][2048];

  const int tid   = threadIdx.x;
  const int wid   = tid >> 6;   // wave 0..7 = head
  const int l     = tid & 63;
  const int frow  = l & 15;
  const int fkq   = l >> 4;
  const int trow0 = fkq * 4;

  // weight fragments for this wave's head: 12 frags = 48 VGPRs
  bf16x8 wf[3][4];
#pragma unroll
  for (int w = 0; w < 3; ++w)
#pragma unroll
    for (int kk = 0; kk < 4; ++kk)
      wf[w][kk] = *(const bf16x8*)(wfrag + ((w * 32 + wid * 4 + kk) * 512) + l * 8);

  // pos*W accumulator-init fragments: 12 VGPRs
  f32x4 posw[3];
#pragma unroll
  for (int w = 0; w < 3; ++w)
    posw[w] = *(const f32x4*)(pw + ((w * 8 + wid) * 64 + l) * 4);

  // pass-through: wave wid covers cols wid*16..wid*16+15; 1 f32x4 per lane
  const int ptcol = wid * 16 + fkq * 4;
  const f32x4 pp = *(const f32x4*)(pos + frow * 128 + ptcol);
  // LDS float index of this lane's pass-through chunk slice (derived from layout)
  const int q    = 4 * wid + fkq;                     // col/4
  const int ptIdx = (((q >> 3) << 1) | (q & 1)) * 256 + (((q & 7) >> 1) * 16 + frow) * 4;

  const f32x4 zero4 = {0.f, 0.f, 0.f, 0.f};

  const int bpi   = gridDim.x * 4;          // batches per iteration (2048)
  const int niter = B / bpi;                // 16
  const int gsb   = frow * 128 + fkq * 8;   // per-lane base within a batch row
  const int bw    = wid >> 1;               // batch this wave stages
  const int c0    = (wid & 1) * 4;          // first chunk this wave stages

  // ---- prologue: stage first 4 batches into buf 0 ----
  {
    const float* xb = xin + (size_t)(blockIdx.x * 4 + bw) * 2048;
#pragma unroll
    for (int j = 0; j < 4; ++j) {
      int c = c0 + j;
      __builtin_amdgcn_global_load_lds((gas_void*)(xb + gsb + (c >> 1) * 32 + (c & 1) * 4),
                                       (las_void*)&lx[0][bw][c * 256], 16, 0, 0);
    }
  }
  int buf = 0;

  for (int it = 0; it < niter; ++it) {
    const int b0 = blockIdx.x * 4 + it * bpi;

    // ---- barrier: this buf's DMAs (issued last iter / prologue) complete ----
    if (it == 0) {
      __syncthreads();
    } else {
      // last iter issue order per wave: 4 DMA then 8 stores; in-order
      // retirement => <=8 outstanding implies all 4 DMAs landed.
      asm volatile("s_waitcnt vmcnt(8)" ::: "memory");
      __builtin_amdgcn_s_barrier();
    }

    // ---- issue next iteration's DMAs first (overlap whole 4-batch body) ----
    if (it + 1 < niter) {
      const float* xb2 = xin + (size_t)(b0 + bpi + bw) * 2048;
#pragma unroll
      for (int j = 0; j < 4; ++j) {
        int c = c0 + j;
        __builtin_amdgcn_global_load_lds((gas_void*)(xb2 + gsb + (c >> 1) * 32 + (c & 1) * 4),
                                         (las_void*)&lx[buf ^ 1][bw][c * 256], 16, 0, 0);
      }
    }
    asm volatile("" ::: "memory");  // pin DMA issue order ahead of body vmem

    // ---- 4 independent batch bodies, xf reloaded from LDS per batch ----
#pragma unroll
    for (int g = 0; g < 4; ++g) {
      const float* lb = &lx[buf][g][0];
      float* ob = out + (size_t)(b0 + g) * 4096;

      bf16x8 xf[4];
#pragma unroll
      for (int kk = 0; kk < 4; ++kk) {
        f32x4 a0 = *(const f32x4*)(lb + (2 * kk + 0) * 256 + l * 4);
        f32x4 a1 = *(const f32x4*)(lb + (2 * kk + 1) * 256 + l * 4);
        xf[kk][0] = (__bf16)a0.x; xf[kk][1] = (__bf16)a0.y;
        xf[kk][2] = (__bf16)a0.z; xf[kk][3] = (__bf16)a0.w;
        xf[kk][4] = (__bf16)a1.x; xf[kk][5] = (__bf16)a1.y;
        xf[kk][6] = (__bf16)a1.z; xf[kk][7] = (__bf16)a1.w;
      }
      // pass-through: out[:, :, 128:256] = x + pos for this wave's 16 cols
      {
        f32x4 c0v = *(const f32x4*)(lb + ptIdx);
        *(f32x4*)(ob + frow * 256 + 128 + ptcol) = c0v + pp;
      }

      // proj (Q,K swapped; V normal) -> attention fully in-register
      f32x4 qa = posw[0], ka = posw[1], va = posw[2];
#pragma unroll
      for (int kk = 0; kk < 4; ++kk) {
        qa = __builtin_amdgcn_mfma_f32_16x16x32_bf16(wf[0][kk], xf[kk], qa, 0, 0, 0);
        ka = __builtin_amdgcn_mfma_f32_16x16x32_bf16(wf[1][kk], xf[kk], ka, 0, 0, 0);
        va = __builtin_amdgcn_mfma_f32_16x16x32_bf16(xf[kk], wf[2][kk], va, 0, 0, 0);
      }
      f16x4 qh, kh, vh;
#pragma unroll
      for (int r = 0; r < 4; ++r) {
        qh[r] = (_Float16)qa[r];
        kh[r] = (_Float16)ka[r];
        vh[r] = (_Float16)va[r];
      }

      // scores^T = K · Q^T (lane holds S^T[s=trow0+r][t=frow]); log2e prefolded
      f32x4 st = __builtin_amdgcn_mfma_f32_16x16x16f16(kh, qh, zero4, 0, 0, 0);
      float p0 = (trow0 + 0 <= frow) ? __builtin_amdgcn_exp2f(st[0]) : 0.f;
      float p1 = (trow0 + 1 <= frow) ? __builtin_amdgcn_exp2f(st[1]) : 0.f;
      float p2 = (trow0 + 2 <= frow) ? __builtin_amdgcn_exp2f(st[2]) : 0.f;
      float p3 = (trow0 + 3 <= frow) ? __builtin_amdgcn_exp2f(st[3]) : 0.f;
      float ssum = (p0 + p1) + (p2 + p3);
      ssum += __shfl_xor(ssum, 16);
      ssum += __shfl_xor(ssum, 32);
      float inv = __builtin_amdgcn_rcpf(ssum);
      f16x4 ah;
      ah[0] = (_Float16)(p0 * inv);
      ah[1] = (_Float16)(p1 * inv);
      ah[2] = (_Float16)(p2 * inv);
      ah[3] = (_Float16)(p3 * inv);

      // o^T = V^T · attn^T (lane holds o[t=frow][d=trow0+r]); relu(o)+o; store
      f32x4 ot = __builtin_amdgcn_mfma_f32_16x16x16f16(vh, ah, zero4, 0, 0, 0);
      f32x4 ov;
#pragma unroll
      for (int r = 0; r < 4; ++r) {
        float x = ot[r];
        ov[r] = x > 0.f ? 2.f * x : x;
      }
      *(f32x4*)(ob + frow * 256 + wid * 16 + trow0) = ov;
    }

    buf ^= 1;
  }
}

extern "C" void kernel_launch(void* const* d_in, const int* in_sizes, int n_in,
                              void* d_out, int out_size, void* d_ws, size_t ws_size,
                              hipStream_t stream) {
  (void)n_in; (void)out_size; (void)ws_size;
  const float* xin = (const float*)d_in[0];
  const float* pos = (const float*)d_in[1];
  const float* Wq  = (const float*)d_in[2];
  const float* Wk  = (const float*)d_in[3];
  const float* Wv  = (const float*)d_in[4];
  float* out = (float*)d_out;
  unsigned short* wf = (unsigned short*)d_ws;            // 96 KiB
  float* pw = (float*)((char*)d_ws + 3 * 8 * 4 * 64 * 8 * sizeof(unsigned short));  // 24 KiB
  int B = in_sizes[0] / 2048;

  hipLaunchKernelGGL(prep_weights, dim3(192), dim3(256), 0, stream, Wq, Wk, Wv, wf);
  hipLaunchKernelGGL(prep_posw, dim3(24), dim3(256), 0, stream, pos, Wq, Wk, Wv, pw);
  hipLaunchKernelGGL(attn_main, dim3(512), dim3(512), 0, stream, xin, pos, wf, pw, out, B);
}

// Round 11
// 170.211 us; speedup vs baseline: 1.0351x; 1.0351x over previous
//
#include <hip/hip_runtime.h>

typedef float    f32x4 __attribute__((ext_vector_type(4)));
typedef __bf16   bf16x8 __attribute__((ext_vector_type(8)));
typedef _Float16 f16x4 __attribute__((ext_vector_type(4)));
typedef unsigned int u32x2 __attribute__((ext_vector_type(2)));

typedef __attribute__((address_space(1))) const void gas_void;
typedef __attribute__((address_space(3))) void las_void;

static __device__ __forceinline__ unsigned short f2bf(float f) {
  union { float f; unsigned int u; } a; a.f = f;
  unsigned int r = (a.u + 0x7FFFu + ((a.u >> 16) & 1u)) >> 16;
  return (unsigned short)r;
}
static __device__ __forceinline__ float bits2f(unsigned int u) {
  union { unsigned int u; float f; } a; a.u = u; return a.f;
}

// 1/sqrt(17) * log2(e): folded into Wq so softmax uses exp2 directly
#define QSCALE_L2E 0.34992146f

// Weights -> bf16 MFMA fragments (A-frag for swapped Q/K proj, B-frag for
// normal V proj; identical lane mapping).
// wf[((w*32 + n*4 + kk)*512) + p*8 + i] = W_w[kk*32+(p>>4)*8+i][n*16+(p&15)]
__global__ void prep_weights(const float* __restrict__ Wq, const float* __restrict__ Wk,
                             const float* __restrict__ Wv, unsigned short* __restrict__ wf) {
  int idx = blockIdx.x * 256 + threadIdx.x;
  if (idx >= 3 * 8 * 4 * 64 * 8) return;
  int i  = idx & 7;
  int p  = (idx >> 3) & 63;
  int kk = (idx >> 9) & 3;
  int n  = (idx >> 11) & 7;
  int w  = idx >> 14;
  const float* W = (w == 0) ? Wq : ((w == 1) ? Wk : Wv);
  float val = W[(kk * 32 + (p >> 4) * 8 + i) * 128 + n * 16 + (p & 15)];
  if (w == 0) val *= QSCALE_L2E;
  wf[idx] = f2bf(val);
}

// R10 pipeline + wave-private convert phase: wave w DMAs its own fp32 chunks,
// waits per-wave vmcnt (no barrier), converts bf16(x+pos) into a
// double-buffered fragment LDS (dedup: conversion done once, not 8x), ONE
// barrier, then DMA(next) + compute-4-batches from bf16 frags.
__global__ void __launch_bounds__(512, 4)
attn_main(const float* __restrict__ xin, const float* __restrict__ pos,
          const unsigned short* __restrict__ wfrag, float* __restrict__ out, int B) {
  // fp32 staging (single-buffer): [batch g][chunk c=0..7][lane*4] ; chunk c
  // holds x[l&15][(c>>1)*32 + (l>>4)*8 + (c&1)*4 .. +3]  (32 KB)
  __shared__ __align__(16) float lx[4][8][256];
  // bf16 fragments (double-buffer): [buf][g][kk][lane*8] ; lane's 8 bf16 =
  // (x+pos)[l&15][kk*32 + (l>>4)*8 .. +7]  (32 KB)
  __shared__ __align__(16) unsigned short lxb[2][4][4][512];

  const int tid   = threadIdx.x;
  const int wid   = tid >> 6;   // wave 0..7 = head
  const int l     = tid & 63;
  const int frow  = l & 15;
  const int fkq   = l >> 4;
  const int trow0 = fkq * 4;

  // weight fragments for this wave's head: 12 frags = 48 regs
  bf16x8 wf[3][4];
#pragma unroll
  for (int w = 0; w < 3; ++w)
#pragma unroll
    for (int kk = 0; kk < 4; ++kk)
      wf[w][kk] = *(const bf16x8*)(wfrag + ((w * 32 + wid * 4 + kk) * 512) + l * 8);

  const int bw = wid >> 1;        // batch this wave stages+converts
  const int c0 = (wid & 1) * 4;   // first chunk this wave stages+converts

  // pos slice for this wave's 4 convert chunks (16 regs)
  f32x4 posc[4];
#pragma unroll
  for (int cc = 0; cc < 4; ++cc) {
    int c = c0 + cc;
    posc[cc] = *(const f32x4*)(pos + frow * 128 + fkq * 8 + (c >> 1) * 32 + (c & 1) * 4);
  }

  // pass-through addressing: wave wid covers cols 128+wid*16 .. +15
  const int ptcol = wid * 16 + fkq * 4;                       // col C (o-space)
  const int ptkk  = wid >> 1;                                 // frag kk of C
  const int ptl   = frow + ((wid & 1) * 2 + (fkq >> 1)) * 16; // owner lane
  const int ptu   = ptl * 8 + (fkq & 1) * 4;                  // u16 index

  const f32x4 zero4 = {0.f, 0.f, 0.f, 0.f};
  const int bpi   = gridDim.x * 4;          // 2048 batches per iteration
  const int niter = B / bpi;                // 16
  const int gsb   = frow * 128 + fkq * 8;   // per-lane base in a batch row

  // ---- prologue: DMA own 4 chunks of batch blockIdx*4+bw into lx ----
  {
    const float* xb = xin + (size_t)(blockIdx.x * 4 + bw) * 2048;
#pragma unroll
    for (int j = 0; j < 4; ++j) {
      int c = c0 + j;
      __builtin_amdgcn_global_load_lds((gas_void*)(xb + gsb + (c >> 1) * 32 + (c & 1) * 4),
                                       (las_void*)&lx[bw][c][0], 16, 0, 0);
    }
  }
  int buf = 0;

  for (int it = 0; it < niter; ++it) {
    const int b0 = blockIdx.x * 4 + it * bpi;

    // ---- per-wave wait: own DMAs landed (no barrier needed: wave reads
    //      only what it DMA'd). After DMA issue last iter we issued 8 stores;
    //      vmcnt(8) => the 4 DMAs retired (in-order). ----
    if (it == 0) asm volatile("s_waitcnt vmcnt(0)" ::: "memory");
    else         asm volatile("s_waitcnt vmcnt(8)" ::: "memory");

    // ---- convert own chunks once: bf16(x+pos) -> lxb[buf][bw][kk] ----
#pragma unroll
    for (int i = 0; i < 2; ++i) {
      int ce = c0 + 2 * i;
      int kk = ce >> 1;
      f32x4 a0 = *(const f32x4*)&lx[bw][ce][l * 4]     + posc[2 * i];
      f32x4 a1 = *(const f32x4*)&lx[bw][ce + 1][l * 4] + posc[2 * i + 1];
      bf16x8 v;
      v[0] = (__bf16)a0.x; v[1] = (__bf16)a0.y; v[2] = (__bf16)a0.z; v[3] = (__bf16)a0.w;
      v[4] = (__bf16)a1.x; v[5] = (__bf16)a1.y; v[6] = (__bf16)a1.z; v[7] = (__bf16)a1.w;
      *(bf16x8*)&lxb[buf][bw][kk][l * 8] = v;
    }
    asm volatile("s_waitcnt lgkmcnt(0)" ::: "memory");
    __builtin_amdgcn_s_barrier();   // lxb[buf] complete for all waves

    // ---- issue next iteration's DMAs (fly under the whole compute phase) ----
    if (it + 1 < niter) {
      const float* xb2 = xin + (size_t)(b0 + bpi + bw) * 2048;
#pragma unroll
      for (int j = 0; j < 4; ++j) {
        int c = c0 + j;
        __builtin_amdgcn_global_load_lds((gas_void*)(xb2 + gsb + (c >> 1) * 32 + (c & 1) * 4),
                                         (las_void*)&lx[bw][c][0], 16, 0, 0);
      }
    }
    asm volatile("" ::: "memory");  // pin DMA issue ahead of body vmem

    // ---- 4 batch bodies from bf16 fragments ----
#pragma unroll
    for (int g = 0; g < 4; ++g) {
      float* ob = out + (size_t)(b0 + g) * 4096;

      bf16x8 xf[4];
#pragma unroll
      for (int kk = 0; kk < 4; ++kk)
        xf[kk] = *(const bf16x8*)&lxb[buf][g][kk][l * 8];

      // pass-through: upconvert 4 bf16 (x+pos) -> fp32, store
      {
        u32x2 pv = *(const u32x2*)&lxb[buf][g][ptkk][ptu];
        f32x4 ptv;
        ptv.x = bits2f(pv[0] << 16);
        ptv.y = bits2f(pv[0] & 0xffff0000u);
        ptv.z = bits2f(pv[1] << 16);
        ptv.w = bits2f(pv[1] & 0xffff0000u);
        *(f32x4*)(ob + frow * 256 + 128 + ptcol) = ptv;
      }

      // proj (Q,K swapped; V normal) -> attention fully in-register
      f32x4 qa = zero4, ka = zero4, va = zero4;
#pragma unroll
      for (int kk = 0; kk < 4; ++kk) {
        qa = __builtin_amdgcn_mfma_f32_16x16x32_bf16(wf[0][kk], xf[kk], qa, 0, 0, 0);
        ka = __builtin_amdgcn_mfma_f32_16x16x32_bf16(wf[1][kk], xf[kk], ka, 0, 0, 0);
        va = __builtin_amdgcn_mfma_f32_16x16x32_bf16(xf[kk], wf[2][kk], va, 0, 0, 0);
      }
      f16x4 qh, kh, vh;
#pragma unroll
      for (int r = 0; r < 4; ++r) {
        qh[r] = (_Float16)qa[r];
        kh[r] = (_Float16)ka[r];
        vh[r] = (_Float16)va[r];
      }

      // scores^T = K · Q^T (lane holds S^T[s=trow0+r][t=frow]); log2e prefolded
      f32x4 st = __builtin_amdgcn_mfma_f32_16x16x16f16(kh, qh, zero4, 0, 0, 0);
      float p0 = (trow0 + 0 <= frow) ? __builtin_amdgcn_exp2f(st[0]) : 0.f;
      float p1 = (trow0 + 1 <= frow) ? __builtin_amdgcn_exp2f(st[1]) : 0.f;
      float p2 = (trow0 + 2 <= frow) ? __builtin_amdgcn_exp2f(st[2]) : 0.f;
      float p3 = (trow0 + 3 <= frow) ? __builtin_amdgcn_exp2f(st[3]) : 0.f;
      float ssum = (p0 + p1) + (p2 + p3);
      ssum += __shfl_xor(ssum, 16);
      ssum += __shfl_xor(ssum, 32);
      float inv = __builtin_amdgcn_rcpf(ssum);
      f16x4 ah;
      ah[0] = (_Float16)(p0 * inv);
      ah[1] = (_Float16)(p1 * inv);
      ah[2] = (_Float16)(p2 * inv);
      ah[3] = (_Float16)(p3 * inv);

      // o^T = V^T · attn^T (lane holds o[t=frow][d=trow0+r]); relu(o)+o; store
      f32x4 ot = __builtin_amdgcn_mfma_f32_16x16x16f16(vh, ah, zero4, 0, 0, 0);
      f32x4 ov;
#pragma unroll
      for (int r = 0; r < 4; ++r) {
        float x = ot[r];
        ov[r] = x > 0.f ? 2.f * x : x;
      }
      *(f32x4*)(ob + frow * 256 + wid * 16 + trow0) = ov;
    }

    buf ^= 1;
  }
}

extern "C" void kernel_launch(void* const* d_in, const int* in_sizes, int n_in,
                              void* d_out, int out_size, void* d_ws, size_t ws_size,
                              hipStream_t stream) {
  (void)n_in; (void)out_size; (void)ws_size;
  const float* xin = (const float*)d_in[0];
  const float* pos = (const float*)d_in[1];
  const float* Wq  = (const float*)d_in[2];
  const float* Wk  = (const float*)d_in[3];
  const float* Wv  = (const float*)d_in[4];
  float* out = (float*)d_out;
  unsigned short* wf = (unsigned short*)d_ws;  // 96 KiB
  int B = in_sizes[0] / 2048;

  hipLaunchKernelGGL(prep_weights, dim3(192), dim3(256), 0, stream, Wq, Wk, Wv, wf);
  hipLaunchKernelGGL(attn_main, dim3(512), dim3(512), 0, stream, xin, pos, wf, out, B);
}

// Round 13
// 169.328 us; speedup vs baseline: 1.0404x; 1.0052x over previous
//
#include <hip/hip_runtime.h>

typedef float    f32x4 __attribute__((ext_vector_type(4)));
typedef __bf16   bf16x8 __attribute__((ext_vector_type(8)));
typedef _Float16 f16x4 __attribute__((ext_vector_type(4)));
typedef unsigned int u32x2 __attribute__((ext_vector_type(2)));

typedef __attribute__((address_space(1))) const void gas_void;
typedef __attribute__((address_space(3))) void las_void;

static __device__ __forceinline__ unsigned short f2bf(float f) {
  union { float f; unsigned int u; } a; a.f = f;
  unsigned int r = (a.u + 0x7FFFu + ((a.u >> 16) & 1u)) >> 16;
  return (unsigned short)r;
}
static __device__ __forceinline__ float bits2f(unsigned int u) {
  union { unsigned int u; float f; } a; a.u = u; return a.f;
}

// 1/sqrt(17) * log2(e): folded into Wq so softmax uses exp2 directly
#define QSCALE_L2E 0.34992146f

// Weights -> bf16 MFMA fragments (A-frag for swapped Q/K proj, B-frag for
// normal V proj; identical lane mapping).
// wf[((w*32 + n*4 + kk)*512) + p*8 + i] = W_w[kk*32+(p>>4)*8+i][n*16+(p&15)]
__global__ void prep_weights(const float* __restrict__ Wq, const float* __restrict__ Wk,
                             const float* __restrict__ Wv, unsigned short* __restrict__ wf) {
  int idx = blockIdx.x * 256 + threadIdx.x;
  if (idx >= 3 * 8 * 4 * 64 * 8) return;
  int i  = idx & 7;
  int p  = (idx >> 3) & 63;
  int kk = (idx >> 9) & 3;
  int n  = (idx >> 11) & 7;
  int w  = idx >> 14;
  const float* W = (w == 0) ? Wq : ((w == 1) ? Wk : Wv);
  float val = W[(kk * 32 + (p >> 4) * 8 + i) * 128 + n * 16 + (p & 15)];
  if (w == 0) val *= QSCALE_L2E;
  wf[idx] = f2bf(val);
}

// R12 linear-DMA + inverse-swizzled-source layout, RACE-FIXED: wave hh DMAs
// rows hh*8..+7 but converts columns kk for ALL rows, so a cross-wave
// s_barrier is required between DMA-landing and convert (per-wave vmcnt only
// covers own DMAs). Swizzle: LDS granule q holds global granule
// (q&~7)|((q&7)^((q>>5)&7)) — involution within 128B lines.
__global__ void __launch_bounds__(512, 4)
attn_main(const float* __restrict__ xin, const float* __restrict__ pos,
          const unsigned short* __restrict__ wfrag, float* __restrict__ out, int B) {
  // fp32 staging (single-buffer): lx[g] = batch g's x, swizzled granules (32KB)
  __shared__ __align__(16) float lx[4][2048];
  // bf16 fragments (double-buffer): [buf][g][kk][lane*8] ; lane's 8 bf16 =
  // (x+pos)[l&15][kk*32 + (l>>4)*8 .. +7]  (32 KB)
  __shared__ __align__(16) unsigned short lxb[2][4][4][512];

  const int tid   = threadIdx.x;
  const int wid   = tid >> 6;   // wave 0..7 = head
  const int l     = tid & 63;
  const int frow  = l & 15;
  const int fkq   = l >> 4;
  const int trow0 = fkq * 4;

  // weight fragments for this wave's head: 12 frags = 48 regs
  bf16x8 wf[3][4];
#pragma unroll
  for (int w = 0; w < 3; ++w)
#pragma unroll
    for (int kk = 0; kk < 4; ++kk)
      wf[w][kk] = *(const bf16x8*)(wfrag + ((w * 32 + wid * 4 + kk) * 512) + l * 8);

  const int bw = wid >> 1;        // batch this wave stages+converts
  const int hh = wid & 1;         // half (1KB / rows) this wave stages

  // pos slice for this wave's 2 convert kk's (16 regs)
  f32x4 posc[4];
#pragma unroll
  for (int i = 0; i < 2; ++i) {
    int kk = hh * 2 + i;
    posc[2 * i + 0] = *(const f32x4*)(pos + frow * 128 + kk * 32 + fkq * 8);
    posc[2 * i + 1] = *(const f32x4*)(pos + frow * 128 + kk * 32 + fkq * 8 + 4);
  }

  // pass-through addressing: wave wid covers cols 128+wid*16 .. +15
  const int ptcol = wid * 16 + fkq * 4;                       // col C (o-space)
  const int ptkk  = wid >> 1;                                 // frag kk of C
  const int ptl   = frow + ((wid & 1) * 2 + (fkq >> 1)) * 16; // owner lane
  const int ptu   = ptl * 8 + (fkq & 1) * 4;                  // u16 index

  const f32x4 zero4 = {0.f, 0.f, 0.f, 0.f};
  const int bpi   = gridDim.x * 4;          // 2048 batches per iteration
  const int niter = B / bpi;                // 16

  // per-lane swizzled global source granule for the 4 linear DMA instructions:
  // p = hh*256 + j*64 + l ; src granule s = (p & ~7) | ((p & 7) ^ ((p>>5) & 7))
  int gsrc[4];
#pragma unroll
  for (int j = 0; j < 4; ++j) {
    int p  = hh * 256 + j * 64 + l;
    int s  = (p & ~7) | ((p & 7) ^ ((p >> 5) & 7));
    gsrc[j] = s * 4;                        // float offset
  }

  // ---- prologue: DMA own half of batch blockIdx*4+bw into lx (linear dest) ----
  {
    const float* xb = xin + (size_t)(blockIdx.x * 4 + bw) * 2048;
#pragma unroll
    for (int j = 0; j < 4; ++j)
      __builtin_amdgcn_global_load_lds((gas_void*)(xb + gsrc[j]),
                                       (las_void*)&lx[bw][(hh * 256 + j * 64) * 4], 16, 0, 0);
  }
  int buf = 0;

  for (int it = 0; it < niter; ++it) {
    const int b0 = blockIdx.x * 4 + it * bpi;

    // ---- wait own DMAs, then BARRIER: convert reads cross-wave rows, so all
    //      waves' DMAs must have landed (per-wave vmcnt is not enough). ----
    if (it == 0) asm volatile("s_waitcnt vmcnt(0)" ::: "memory");
    else         asm volatile("s_waitcnt vmcnt(8)" ::: "memory");
    __builtin_amdgcn_s_barrier();

    // ---- convert own columns once: bf16(x+pos) -> lxb[buf][bw][kk] ----
#pragma unroll
    for (int i = 0; i < 2; ++i) {
      int kk  = hh * 2 + i;
      int q0  = frow * 32 + kk * 8 + fkq * 2;
      int q0s = (q0 & ~7) | ((q0 & 7) ^ (frow & 7));
      f32x4 a0 = *(const f32x4*)&lx[bw][q0s * 4]       + posc[2 * i];
      f32x4 a1 = *(const f32x4*)&lx[bw][(q0s ^ 1) * 4] + posc[2 * i + 1];
      bf16x8 v;
      v[0] = (__bf16)a0.x; v[1] = (__bf16)a0.y; v[2] = (__bf16)a0.z; v[3] = (__bf16)a0.w;
      v[4] = (__bf16)a1.x; v[5] = (__bf16)a1.y; v[6] = (__bf16)a1.z; v[7] = (__bf16)a1.w;
      *(bf16x8*)&lxb[buf][bw][kk][l * 8] = v;
    }
    asm volatile("s_waitcnt lgkmcnt(0)" ::: "memory");
    __builtin_amdgcn_s_barrier();   // lxb[buf] complete; lx reads all drained

    // ---- issue next iteration's DMAs (fly under the whole compute phase) ----
    if (it + 1 < niter) {
      const float* xb2 = xin + (size_t)(b0 + bpi + bw) * 2048;
#pragma unroll
      for (int j = 0; j < 4; ++j)
        __builtin_amdgcn_global_load_lds((gas_void*)(xb2 + gsrc[j]),
                                         (las_void*)&lx[bw][(hh * 256 + j * 64) * 4], 16, 0, 0);
    }
    asm volatile("" ::: "memory");  // pin DMA issue ahead of body vmem

    // ---- 4 batch bodies from bf16 fragments ----
#pragma unroll
    for (int g = 0; g < 4; ++g) {
      float* ob = out + (size_t)(b0 + g) * 4096;

      bf16x8 xf[4];
#pragma unroll
      for (int kk = 0; kk < 4; ++kk)
        xf[kk] = *(const bf16x8*)&lxb[buf][g][kk][l * 8];

      // pass-through: upconvert 4 bf16 (x+pos) -> fp32, store
      {
        u32x2 pv = *(const u32x2*)&lxb[buf][g][ptkk][ptu];
        f32x4 ptv;
        ptv.x = bits2f(pv[0] << 16);
        ptv.y = bits2f(pv[0] & 0xffff0000u);
        ptv.z = bits2f(pv[1] << 16);
        ptv.w = bits2f(pv[1] & 0xffff0000u);
        *(f32x4*)(ob + frow * 256 + 128 + ptcol) = ptv;
      }

      // proj (Q,K swapped; V normal) -> attention fully in-register
      f32x4 qa = zero4, ka = zero4, va = zero4;
#pragma unroll
      for (int kk = 0; kk < 4; ++kk) {
        qa = __builtin_amdgcn_mfma_f32_16x16x32_bf16(wf[0][kk], xf[kk], qa, 0, 0, 0);
        ka = __builtin_amdgcn_mfma_f32_16x16x32_bf16(wf[1][kk], xf[kk], ka, 0, 0, 0);
        va = __builtin_amdgcn_mfma_f32_16x16x32_bf16(xf[kk], wf[2][kk], va, 0, 0, 0);
      }
      f16x4 qh, kh, vh;
#pragma unroll
      for (int r = 0; r < 4; ++r) {
        qh[r] = (_Float16)qa[r];
        kh[r] = (_Float16)ka[r];
        vh[r] = (_Float16)va[r];
      }

      // scores^T = K · Q^T (lane holds S^T[s=trow0+r][t=frow]); log2e prefolded
      f32x4 st = __builtin_amdgcn_mfma_f32_16x16x16f16(kh, qh, zero4, 0, 0, 0);
      float p0 = (trow0 + 0 <= frow) ? __builtin_amdgcn_exp2f(st[0]) : 0.f;
      float p1 = (trow0 + 1 <= frow) ? __builtin_amdgcn_exp2f(st[1]) : 0.f;
      float p2 = (trow0 + 2 <= frow) ? __builtin_amdgcn_exp2f(st[2]) : 0.f;
      float p3 = (trow0 + 3 <= frow) ? __builtin_amdgcn_exp2f(st[3]) : 0.f;
      float ssum = (p0 + p1) + (p2 + p3);
      ssum += __shfl_xor(ssum, 16);
      ssum += __shfl_xor(ssum, 32);
      float inv = __builtin_amdgcn_rcpf(ssum);
      f16x4 ah;
      ah[0] = (_Float16)(p0 * inv);
      ah[1] = (_Float16)(p1 * inv);
      ah[2] = (_Float16)(p2 * inv);
      ah[3] = (_Float16)(p3 * inv);

      // o^T = V^T · attn^T (lane holds o[t=frow][d=trow0+r]); relu(o)+o; store
      f32x4 ot = __builtin_amdgcn_mfma_f32_16x16x16f16(vh, ah, zero4, 0, 0, 0);
      f32x4 ov;
#pragma unroll
      for (int r = 0; r < 4; ++r) {
        float x = ot[r];
        ov[r] = x > 0.f ? 2.f * x : x;
      }
      *(f32x4*)(ob + frow * 256 + wid * 16 + trow0) = ov;
    }

    buf ^= 1;
  }
}

extern "C" void kernel_launch(void* const* d_in, const int* in_sizes, int n_in,
                              void* d_out, int out_size, void* d_ws, size_t ws_size,
                              hipStream_t stream) {
  (void)n_in; (void)out_size; (void)ws_size;
  const float* xin = (const float*)d_in[0];
  const float* pos = (const float*)d_in[1];
  const float* Wq  = (const float*)d_in[2];
  const float* Wk  = (const float*)d_in[3];
  const float* Wv  = (const float*)d_in[4];
  float* out = (float*)d_out;
  unsigned short* wf = (unsigned short*)d_ws;  // 96 KiB
  int B = in_sizes[0] / 2048;

  hipLaunchKernelGGL(prep_weights, dim3(192), dim3(256), 0, stream, Wq, Wk, Wv, wf);
  hipLaunchKernelGGL(attn_main, dim3(512), dim3(512), 0, stream, xin, pos, wf, out, B);
}